// Round 15
// baseline (420.116 us; speedup 1.0000x reference)
//
#include <hip/hip_runtime.h>
#include <cstddef>
#include <cstdint>

// SelfAttention_71571335020783 on MI355X (gfx950)
// fp16 MFMA, BK=32, 3-buffer LDS pipeline with counted vmcnt (T4).
constexpr int E     = 2048;
constexpr int SEQ   = 2048;
constexpr int BATCH = 2;
constexpr int BS    = BATCH * SEQ;   // 4096

constexpr int BM = 128, BN = 128, BK = 32;
constexpr int NBUF = 3;              // 3 x 8KB per operand = 48KB LDS/block

typedef _Float16 f16;
typedef f16  f16x4 __attribute__((ext_vector_type(4)));
typedef f16  f16x8 __attribute__((ext_vector_type(8)));
typedef float f32x4 __attribute__((ext_vector_type(4)));

#define GLOAD16(g, l)                                                   \
    __builtin_amdgcn_global_load_lds(                                   \
        (const __attribute__((address_space(1))) void*)(g),             \
        (__attribute__((address_space(3))) void*)(l), 16, 0, 0)

// counted waitcnt (immediate must be literal) + raw barrier (no vmcnt drain)
#define VMCNT(n) asm volatile("s_waitcnt vmcnt(" #n ")" ::: "memory")
#define BARRIER()                                                       \
    do { asm volatile("" ::: "memory");                                 \
         __builtin_amdgcn_s_barrier();                                  \
         asm volatile("" ::: "memory"); } while (0)

// chunk swizzle for [128 rows][4 chunks of 8 f16]: 2-way max on b128 quads
__device__ __forceinline__ int swz4(int r) { return (r & 3) ^ ((r >> 2) & 3); }

// ---------------------------------------------------------------------------
// Pipelined K-loop core: acc += A[m0..+128,:K] * B[n0..+128,:K]^T.
// Both operands k-contiguous. 2-ahead prefetch, vmcnt(8) steady state
// (2 stages x 4 loads/thread in flight), raw barriers.
// ---------------------------------------------------------------------------
__device__ __forceinline__ void gemm_core(
    const f16* __restrict__ Ab, const f16* __restrict__ Bb,
    int K, int lda, int ldb, int m0, int n0,
    f16* At, f16* Bt, f32x4 acc[4][4])
{
    const int tid = threadIdx.x;
    const int l  = tid & 63;
    const int w  = tid >> 6;
    const int lr = l & 15;
    const int hi = l >> 4;             // k-chunk 0..3 (8 f16 each)
    const int wm = (w >> 1) * 64;
    const int wn = (w & 1) * 64;

    auto stage = [&](int buf, int k0) {
#pragma unroll
        for (int p = 0; p < 2; ++p) {
            const int ci  = p * 256 + tid;          // 16B slot 0..511
            const int row = ci >> 2;
            const int lc  = (ci & 3) ^ swz4(row);   // pre-swizzled source chunk
            GLOAD16(Ab + (size_t)(m0 + row) * lda + k0 + lc * 8,
                    At + buf * 4096 + p * 2048 + w * 512);
            GLOAD16(Bb + (size_t)(n0 + row) * ldb + k0 + lc * 8,
                    Bt + buf * 4096 + p * 2048 + w * 512);
        }
    };

    const int NT = K / BK;
    stage(0, 0);
    stage(1, BK);

    int cur = 0, sb = 2;
    for (int t = 0; t < NT; ++t) {
        // stage 2 tiles ahead; wait so tile t is fully landed, newer stay out
        if (t + 2 < NT) { stage(sb, (t + 2) * BK); VMCNT(8); }
        else if (t + 1 < NT) { VMCNT(4); }
        else { VMCNT(0); }
        BARRIER();                      // all waves' tile-t loads landed

        const f16* Ac = At + cur * 4096;
        const f16* Bc = Bt + cur * 4096;
        f16x8 af[4], bf[4];
#pragma unroll
        for (int i = 0; i < 4; ++i) {
            const int ar = wm + i * 16 + lr;
            af[i] = *reinterpret_cast<const f16x8*>(Ac + ar * 32 + (hi ^ swz4(ar)) * 8);
            const int br = wn + i * 16 + lr;
            bf[i] = *reinterpret_cast<const f16x8*>(Bc + br * 32 + (hi ^ swz4(br)) * 8);
        }
#pragma unroll
        for (int i = 0; i < 4; ++i)
#pragma unroll
            for (int j = 0; j < 4; ++j)
                acc[i][j] = __builtin_amdgcn_mfma_f32_16x16x32_f16(
                    af[i], bf[j], acc[i][j], 0, 0, 0);

        BARRIER();                      // protect buf reuse by next stage
        cur = (cur == NBUF - 1) ? 0 : cur + 1;
        sb  = (sb  == NBUF - 1) ? 0 : sb  + 1;
    }
}

__device__ __forceinline__ void swz_block(int gx, int gy, int& bx, int& by)
{
    const int nwg  = gx * gy;                  // all our grids: nwg % 8 == 0
    const int flat = blockIdx.y * gx + blockIdx.x;
    const int cpx  = nwg >> 3;
    const int swz  = (flat & 7) * cpx + (flat >> 3);
    bx = swz % gx;
    by = swz / gx;
}

// ---------------------------------------------------------------------------
// Generic GEMM: C[m,n] = alpha * sum_k A[m,k]*B[n,k].  EPI 0: row-major CT.
// EPI 1: transposed per-batch fp16 C[b*2048^2 + n*2048 + (m&2047)].
// ---------------------------------------------------------------------------
template <int EPI, typename CT>
__global__ __launch_bounds__(256) void gemm_f16(
    const f16* __restrict__ A, const f16* __restrict__ B, CT* __restrict__ C,
    int K, int lda, int ldb, int ldc,
    long long sA, long long sB, long long sC, float alpha)
{
    alignas(16) __shared__ f16 At[NBUF * BM * BK];   // 24 KB
    alignas(16) __shared__ f16 Bt[NBUF * BN * BK];   // 24 KB

    int bx, by; swz_block(gridDim.x, gridDim.y, bx, by);
    const int m0 = by * BM, n0 = bx * BN;

    f32x4 acc[4][4] = {};
    gemm_core(A + (size_t)blockIdx.z * sA, B + (size_t)blockIdx.z * sB,
              K, lda, ldb, m0, n0, At, Bt, acc);

    const int l  = threadIdx.x & 63;
    const int w  = threadIdx.x >> 6;
    const int lr = l & 15, hi = l >> 4;
    const int wm = (w >> 1) * 64, wn = (w & 1) * 64;

    if (EPI == 0) {
        CT* Cb = C + (size_t)blockIdx.z * sC;
#pragma unroll
        for (int i = 0; i < 4; ++i)
#pragma unroll
            for (int r = 0; r < 4; ++r) {
                const int row = m0 + wm + i * 16 + hi * 4 + r;
#pragma unroll
                for (int j = 0; j < 4; ++j) {
                    const int col = n0 + wn + j * 16 + lr;
                    Cb[(size_t)row * ldc + col] = (CT)(alpha * acc[i][j][r]);
                }
            }
    } else {
        f16* Cb = (f16*)C;
#pragma unroll
        for (int i = 0; i < 4; ++i) {
            const int rowb = m0 + wm + i * 16 + hi * 4;
            const long long base = ((long long)(rowb >> 11) << 22) + (rowb & 2047);
#pragma unroll
            for (int j = 0; j < 4; ++j) {
                const int col = n0 + wn + j * 16 + lr;
                f16x4 v = {(f16)(alpha * acc[i][j][0]), (f16)(alpha * acc[i][j][1]),
                           (f16)(alpha * acc[i][j][2]), (f16)(alpha * acc[i][j][3])};
                *reinterpret_cast<f16x4*>(Cb + base + (long long)col * 2048) = v;
            }
        }
    }
}

// ---------------------------------------------------------------------------
// Merged QKV projection: grid (16, 32, 3). z=0 QT, z=1 KT (transposed epi),
// z=2 V (row-major). A = xc for all z.
// ---------------------------------------------------------------------------
__global__ __launch_bounds__(256) void qkv_f16(
    const f16* __restrict__ xc,
    const f16* __restrict__ WqT, const f16* __restrict__ WkT,
    const f16* __restrict__ WvT,
    f16* __restrict__ QT, f16* __restrict__ KT, f16* __restrict__ V)
{
    alignas(16) __shared__ f16 At[NBUF * BM * BK];
    alignas(16) __shared__ f16 Bt[NBUF * BN * BK];

    const int z = blockIdx.z;
    const f16* B = (z == 0) ? WqT : (z == 1) ? WkT : WvT;

    int bx, by; swz_block(gridDim.x, gridDim.y, bx, by);
    const int m0 = by * BM, n0 = bx * BN;

    f32x4 acc[4][4] = {};
    gemm_core(xc, B, E, E, E, m0, n0, At, Bt, acc);

    const int l  = threadIdx.x & 63;
    const int w  = threadIdx.x >> 6;
    const int lr = l & 15, hi = l >> 4;
    const int wm = (w >> 1) * 64, wn = (w & 1) * 64;

    if (z == 2) {
#pragma unroll
        for (int i = 0; i < 4; ++i)
#pragma unroll
            for (int r = 0; r < 4; ++r) {
                const int row = m0 + wm + i * 16 + hi * 4 + r;
#pragma unroll
                for (int j = 0; j < 4; ++j) {
                    const int col = n0 + wn + j * 16 + lr;
                    V[(size_t)row * E + col] = (f16)acc[i][j][r];
                }
            }
    } else {
        f16* Cb = (z == 0) ? QT : KT;
#pragma unroll
        for (int i = 0; i < 4; ++i) {
            const int rowb = m0 + wm + i * 16 + hi * 4;
            const long long base = ((long long)(rowb >> 11) << 22) + (rowb & 2047);
#pragma unroll
            for (int j = 0; j < 4; ++j) {
                const int col = n0 + wn + j * 16 + lr;
                f16x4 v = {(f16)acc[i][j][0], (f16)acc[i][j][1],
                           (f16)acc[i][j][2], (f16)acc[i][j][3]};
                *reinterpret_cast<f16x4*>(Cb + base + (long long)col * 2048) = v;
            }
        }
    }
}

// ---------------------------------------------------------------------------
__global__ __launch_bounds__(256) void conv_x_f16(
    const float* __restrict__ x, f16* __restrict__ xc, int n4)
{
    int i = blockIdx.x * 256 + threadIdx.x;
    const int stride = gridDim.x * 256;
    for (; i < n4; i += stride) {
        const float4 v = reinterpret_cast<const float4*>(x)[i];
        f16x4 h = {(f16)v.x, (f16)v.y, (f16)v.z, (f16)v.w};
        reinterpret_cast<f16x4*>(xc)[i] = h;
    }
}

__global__ __launch_bounds__(256) void conv_wT(
    const float* __restrict__ W0, const float* __restrict__ W1,
    const float* __restrict__ W2, const float* __restrict__ W3,
    f16* __restrict__ O0, f16* __restrict__ O1,
    f16* __restrict__ O2, f16* __restrict__ O3)
{
    const float* src; f16* dst;
    switch (blockIdx.z) {
        case 0: src = W0; dst = O0; break;
        case 1: src = W1; dst = O1; break;
        case 2: src = W2; dst = O2; break;
        default: src = W3; dst = O3; break;
    }
    __shared__ f16 t[64][68];
    const int e0 = blockIdx.y * 64, f0 = blockIdx.x * 64;
    const int tid = threadIdx.x;
    const int tf = (tid & 15) * 4;
    const int te = tid >> 4;
#pragma unroll
    for (int p = 0; p < 4; ++p) {
        const int e = te + p * 16;
        const float4 v = *reinterpret_cast<const float4*>(
            &src[(size_t)(e0 + e) * 2048 + f0 + tf]);
        t[tf + 0][e] = (f16)v.x; t[tf + 1][e] = (f16)v.y;
        t[tf + 2][e] = (f16)v.z; t[tf + 3][e] = (f16)v.w;
    }
    __syncthreads();
#pragma unroll
    for (int p = 0; p < 4; ++p) {
        const int f = (tid >> 4) + p * 16;
        const int e = (tid & 15) * 4;
        const f16x4 v = *reinterpret_cast<const f16x4*>(&t[f][e]);
        *reinterpret_cast<f16x4*>(&dst[(size_t)(f0 + f) * 2048 + e0 + e]) = v;
    }
}

__global__ __launch_bounds__(256) void softmax_rows_f16(
    const float* __restrict__ S, f16* __restrict__ A)
{
    const float* row = S + (size_t)blockIdx.x * 2048;
    f16* arow = A + (size_t)blockIdx.x * 2048;
    const int tid = threadIdx.x;

    float4 v0 = reinterpret_cast<const float4*>(row)[tid];
    float4 v1 = reinterpret_cast<const float4*>(row)[tid + 256];

    float m = fmaxf(fmaxf(fmaxf(v0.x, v0.y), fmaxf(v0.z, v0.w)),
                    fmaxf(fmaxf(v1.x, v1.y), fmaxf(v1.z, v1.w)));
#pragma unroll
    for (int off = 32; off > 0; off >>= 1) m = fmaxf(m, __shfl_xor(m, off));

    __shared__ float red[8];
    if ((tid & 63) == 0) red[tid >> 6] = m;
    __syncthreads();
    m = fmaxf(fmaxf(red[0], red[1]), fmaxf(red[2], red[3]));

    v0.x = __expf(v0.x - m); v0.y = __expf(v0.y - m);
    v0.z = __expf(v0.z - m); v0.w = __expf(v0.w - m);
    v1.x = __expf(v1.x - m); v1.y = __expf(v1.y - m);
    v1.z = __expf(v1.z - m); v1.w = __expf(v1.w - m);

    float s = v0.x + v0.y + v0.z + v0.w + v1.x + v1.y + v1.z + v1.w;
#pragma unroll
    for (int off = 32; off > 0; off >>= 1) s += __shfl_xor(s, off);
    if ((tid & 63) == 0) red[4 + (tid >> 6)] = s;
    __syncthreads();
    s = red[4] + red[5] + red[6] + red[7];

    const float inv = 1.0f / s;
    f16x4 a0 = {(f16)(v0.x * inv), (f16)(v0.y * inv), (f16)(v0.z * inv), (f16)(v0.w * inv)};
    f16x4 a1 = {(f16)(v1.x * inv), (f16)(v1.y * inv), (f16)(v1.z * inv), (f16)(v1.w * inv)};
    reinterpret_cast<f16x4*>(arow)[tid]       = a0;
    reinterpret_cast<f16x4*>(arow)[tid + 256] = a1;
}

// ---------------------------------------------------------------------------
extern "C" void kernel_launch(void* const* d_in, const int* in_sizes, int n_in,
                              void* d_out, int out_size, void* d_ws, size_t ws_size,
                              hipStream_t stream)
{
    const float* x  = (const float*)d_in[0];  // [2,2048,2048] == [4096,2048]
    const float* Wq = (const float*)d_in[1];
    const float* Wk = (const float*)d_in[2];
    const float* Wv = (const float*)d_in[3];
    const float* Wo = (const float*)d_in[4];
    float* out = (float*)d_out;               // [4096,2048] fp32

    // ws: xc | WqT WkT WvT WoT | QT | KT | V | S(fp32).  A=QT, AO=KT reuse.
    f16* ws16 = (f16*)d_ws;
    const size_t MATE = (size_t)BS * E;       // 8,388,608
    const size_t WMAT = (size_t)E * E;        // 4,194,304
    f16* xc  = ws16;
    f16* WqT = xc  + MATE;
    f16* WkT = WqT + WMAT;
    f16* WvT = WkT + WMAT;
    f16* WoT = WvT + WMAT;
    f16* QT  = WoT + WMAT;                    // [2][2048 f][2048 s]
    f16* KT  = QT  + MATE;
    f16* V   = KT  + MATE;                    // [4096 s][2048 f]
    float* S = (float*)(V + MATE);            // [2][2048 e][2048 f]
    f16* A   = QT;                            // reuse
    f16* AO  = KT;                            // reuse

    const dim3 blk(256);
    const long long BMATL = (long long)E * E;

    // 0) converters
    hipLaunchKernelGGL(conv_x_f16, dim3(2048), blk, 0, stream, x, xc, (int)(MATE / 4));
    hipLaunchKernelGGL(conv_wT, dim3(32, 32, 4), blk, 0, stream,
                       Wq, Wk, Wv, Wo, WqT, WkT, WvT, WoT);

    const dim3 gBig(E / BN, BS / BM, 1);      // 16 x 32
    const dim3 gSq (E / BN, E  / BM, BATCH);  // 16 x 16 x 2

    // 1) merged QKV: z=0 QT, z=1 KT (transposed epi), z=2 V (row-major)
    hipLaunchKernelGGL(qkv_f16, dim3(E / BN, BS / BM, 3), blk, 0, stream,
                       xc, WqT, WkT, WvT, QT, KT, V);

    // 2) S_b[e,f] = (1/8) * sum_s QT_b[e,s] KT_b[f,s]  -> fp32
    hipLaunchKernelGGL((gemm_f16<0, float>), gSq, blk, 0, stream,
                       QT, KT, S, SEQ, E, E, E, BMATL, BMATL, BMATL, 0.125f);

    // 3) softmax rows -> fp16 A
    hipLaunchKernelGGL(softmax_rows_f16, dim3(BATCH * E), blk, 0, stream, S, A);

    // 4) AO_b[s,e] = sum_f V_b[s,f] A_b[e,f]  -> fp16
    hipLaunchKernelGGL((gemm_f16<0, f16>), gSq, blk, 0, stream,
                       V, A, AO, E, E, E, E, BMATL, BMATL, BMATL, 1.0f);

    // 5) out = AO @ Wo  (B = WoT, k-contiguous) -> fp32
    hipLaunchKernelGGL((gemm_f16<0, float>), gBig, blk, 0, stream,
                       AO, WoT, out, E, E, E, E, 0LL, 0LL, 0LL, 1.0f);
}

// Round 18
// 394.998 us; speedup vs baseline: 1.0636x; 1.0636x over previous
//
#include <hip/hip_runtime.h>
#include <cstddef>
#include <cstdint>

// SelfAttention_71571335020783 on MI355X (gfx950)
// fp16 MFMA, BK=64 (conflict-free layout, R13) + counted-vmcnt 2-buffer
// pipeline (R15's proven sync): tile t+1's loads stay in flight across
// the barriers while tile t computes.
constexpr int E     = 2048;
constexpr int SEQ   = 2048;
constexpr int BATCH = 2;
constexpr int BS    = BATCH * SEQ;   // 4096

constexpr int BM = 128, BN = 128, BK = 64;

typedef _Float16 f16;
typedef f16  f16x4 __attribute__((ext_vector_type(4)));
typedef f16  f16x8 __attribute__((ext_vector_type(8)));
typedef float f32x4 __attribute__((ext_vector_type(4)));

#define GLOAD16(g, l)                                                   \
    __builtin_amdgcn_global_load_lds(                                   \
        (const __attribute__((address_space(1))) void*)(g),             \
        (__attribute__((address_space(3))) void*)(l), 16, 0, 0)

#define VMCNT(n) asm volatile("s_waitcnt vmcnt(" #n ")" ::: "memory")
#define BARRIER()                                                       \
    do { asm volatile("" ::: "memory");                                 \
         __builtin_amdgcn_s_barrier();                                  \
         asm volatile("" ::: "memory"); } while (0)

// ---------------------------------------------------------------------------
// Pipelined K-loop: acc += A[m0..+128,:K] * B[n0..+128,:K]^T, k-contiguous
// operands. LDS [2 bufs][128 rows][8 chunks of 8 f16], chunk ^= (row&7)
// (128B rows span all 32 banks: measured 0 conflicts). Per iter:
//   stage(t+1) -> vmcnt(8): tile t landed, t+1 in flight
//   barrier -> ds_read+MFMA(t) -> barrier (protects buf overwrite at t+1)
// ---------------------------------------------------------------------------
__device__ __forceinline__ void gemm_core(
    const f16* __restrict__ Ab, const f16* __restrict__ Bb,
    int K, int lda, int ldb, int m0, int n0,
    f16* At, f16* Bt, f32x4 acc[4][4])
{
    const int tid = threadIdx.x;
    const int l  = tid & 63;
    const int w  = tid >> 6;
    const int lr = l & 15;
    const int hi = l >> 4;
    const int wm = (w >> 1) * 64;
    const int wn = (w & 1) * 64;

    auto stage = [&](int buf, int k0) {
#pragma unroll
        for (int p = 0; p < 4; ++p) {
            const int ci  = p * 256 + tid;          // 16B slot 0..1023
            const int row = ci >> 3;
            const int sc  = (ci & 7) ^ (row & 7);   // pre-swizzled source chunk
            GLOAD16(Ab + (size_t)(m0 + row) * lda + k0 + sc * 8,
                    At + buf * (BM * BK) + p * 2048 + w * 512);
            GLOAD16(Bb + (size_t)(n0 + row) * ldb + k0 + sc * 8,
                    Bt + buf * (BN * BK) + p * 2048 + w * 512);
        }
    };

    const int NT = K / BK;
    stage(0, 0);                       // 8 loads/thread outstanding

    int cur = 0;
    for (int t = 0; t < NT; ++t) {
        if (t + 1 < NT) { stage(cur ^ 1, (t + 1) * BK); VMCNT(8); }
        else            { VMCNT(0); }
        BARRIER();                      // all waves' tile-t loads landed

        const f16* Ac = At + cur * (BM * BK);
        const f16* Bc = Bt + cur * (BN * BK);
        f16x8 af[4][2], bf[4][2];
#pragma unroll
        for (int i = 0; i < 4; ++i)
#pragma unroll
            for (int ks = 0; ks < 2; ++ks) {
                const int ar = wm + i * 16 + lr;
                const int ap = (ks * 4 + hi) ^ (ar & 7);
                af[i][ks] = *reinterpret_cast<const f16x8*>(Ac + ar * 64 + ap * 8);
                const int br = wn + i * 16 + lr;
                const int bp = (ks * 4 + hi) ^ (br & 7);
                bf[i][ks] = *reinterpret_cast<const f16x8*>(Bc + br * 64 + bp * 8);
            }
#pragma unroll
        for (int ks = 0; ks < 2; ++ks)
#pragma unroll
            for (int i = 0; i < 4; ++i)
#pragma unroll
                for (int j = 0; j < 4; ++j)
                    acc[i][j] = __builtin_amdgcn_mfma_f32_16x16x32_f16(
                        af[i][ks], bf[j][ks], acc[i][j], 0, 0, 0);

        BARRIER();                      // buf reuse protection
        cur ^= 1;
    }
}

__device__ __forceinline__ void swz_block(int gx, int gy, int& bx, int& by)
{
    const int nwg  = gx * gy;                  // all our grids: nwg % 8 == 0
    const int flat = blockIdx.y * gx + blockIdx.x;
    const int cpx  = nwg >> 3;
    const int swz  = (flat & 7) * cpx + (flat >> 3);
    bx = swz % gx;
    by = swz / gx;
}

// ---------------------------------------------------------------------------
// Generic GEMM: C[m,n] = alpha * sum_k A[m,k]*B[n,k].  EPI 0: row-major CT.
// EPI 1: transposed per-batch fp16 C[b*2048^2 + n*2048 + (m&2047)].
// ---------------------------------------------------------------------------
template <int EPI, typename CT>
__global__ __launch_bounds__(256) void gemm_f16(
    const f16* __restrict__ A, const f16* __restrict__ B, CT* __restrict__ C,
    int K, int lda, int ldb, int ldc,
    long long sA, long long sB, long long sC, float alpha)
{
    alignas(16) __shared__ f16 At[2 * BM * BK];   // 32 KB
    alignas(16) __shared__ f16 Bt[2 * BN * BK];   // 32 KB

    int bx, by; swz_block(gridDim.x, gridDim.y, bx, by);
    const int m0 = by * BM, n0 = bx * BN;

    f32x4 acc[4][4] = {};
    gemm_core(A + (size_t)blockIdx.z * sA, B + (size_t)blockIdx.z * sB,
              K, lda, ldb, m0, n0, At, Bt, acc);

    const int l  = threadIdx.x & 63;
    const int w  = threadIdx.x >> 6;
    const int lr = l & 15, hi = l >> 4;
    const int wm = (w >> 1) * 64, wn = (w & 1) * 64;

    if (EPI == 0) {
        CT* Cb = C + (size_t)blockIdx.z * sC;
#pragma unroll
        for (int i = 0; i < 4; ++i)
#pragma unroll
            for (int r = 0; r < 4; ++r) {
                const int row = m0 + wm + i * 16 + hi * 4 + r;
#pragma unroll
                for (int j = 0; j < 4; ++j) {
                    const int col = n0 + wn + j * 16 + lr;
                    Cb[(size_t)row * ldc + col] = (CT)(alpha * acc[i][j][r]);
                }
            }
    } else {
        f16* Cb = (f16*)C;
#pragma unroll
        for (int i = 0; i < 4; ++i) {
            const int rowb = m0 + wm + i * 16 + hi * 4;
            const long long base = ((long long)(rowb >> 11) << 22) + (rowb & 2047);
#pragma unroll
            for (int j = 0; j < 4; ++j) {
                const int col = n0 + wn + j * 16 + lr;
                f16x4 v = {(f16)(alpha * acc[i][j][0]), (f16)(alpha * acc[i][j][1]),
                           (f16)(alpha * acc[i][j][2]), (f16)(alpha * acc[i][j][3])};
                *reinterpret_cast<f16x4*>(Cb + base + (long long)col * 2048) = v;
            }
        }
    }
}

// ---------------------------------------------------------------------------
// Merged QKV projection: grid (16, 32, 3). z=0 QT, z=1 KT (transposed epi),
// z=2 V (row-major). A = xc for all z.
// ---------------------------------------------------------------------------
__global__ __launch_bounds__(256) void qkv_f16(
    const f16* __restrict__ xc,
    const f16* __restrict__ WqT, const f16* __restrict__ WkT,
    const f16* __restrict__ WvT,
    f16* __restrict__ QT, f16* __restrict__ KT, f16* __restrict__ V)
{
    alignas(16) __shared__ f16 At[2 * BM * BK];
    alignas(16) __shared__ f16 Bt[2 * BN * BK];

    const int z = blockIdx.z;
    const f16* B = (z == 0) ? WqT : (z == 1) ? WkT : WvT;

    int bx, by; swz_block(gridDim.x, gridDim.y, bx, by);
    const int m0 = by * BM, n0 = bx * BN;

    f32x4 acc[4][4] = {};
    gemm_core(xc, B, E, E, E, m0, n0, At, Bt, acc);

    const int l  = threadIdx.x & 63;
    const int w  = threadIdx.x >> 6;
    const int lr = l & 15, hi = l >> 4;
    const int wm = (w >> 1) * 64, wn = (w & 1) * 64;

    if (z == 2) {
#pragma unroll
        for (int i = 0; i < 4; ++i)
#pragma unroll
            for (int r = 0; r < 4; ++r) {
                const int row = m0 + wm + i * 16 + hi * 4 + r;
#pragma unroll
                for (int j = 0; j < 4; ++j) {
                    const int col = n0 + wn + j * 16 + lr;
                    V[(size_t)row * E + col] = (f16)acc[i][j][r];
                }
            }
    } else {
        f16* Cb = (z == 0) ? QT : KT;
#pragma unroll
        for (int i = 0; i < 4; ++i) {
            const int rowb = m0 + wm + i * 16 + hi * 4;
            const long long base = ((long long)(rowb >> 11) << 22) + (rowb & 2047);
#pragma unroll
            for (int j = 0; j < 4; ++j) {
                const int col = n0 + wn + j * 16 + lr;
                f16x4 v = {(f16)acc[i][j][0], (f16)acc[i][j][1],
                           (f16)acc[i][j][2], (f16)acc[i][j][3]};
                *reinterpret_cast<f16x4*>(Cb + base + (long long)col * 2048) = v;
            }
        }
    }
}

// ---------------------------------------------------------------------------
__global__ __launch_bounds__(256) void conv_x_f16(
    const float* __restrict__ x, f16* __restrict__ xc, int n4)
{
    int i = blockIdx.x * 256 + threadIdx.x;
    const int stride = gridDim.x * 256;
    for (; i < n4; i += stride) {
        const float4 v = reinterpret_cast<const float4*>(x)[i];
        f16x4 h = {(f16)v.x, (f16)v.y, (f16)v.z, (f16)v.w};
        reinterpret_cast<f16x4*>(xc)[i] = h;
    }
}

__global__ __launch_bounds__(256) void conv_wT(
    const float* __restrict__ W0, const float* __restrict__ W1,
    const float* __restrict__ W2, const float* __restrict__ W3,
    f16* __restrict__ O0, f16* __restrict__ O1,
    f16* __restrict__ O2, f16* __restrict__ O3)
{
    const float* src; f16* dst;
    switch (blockIdx.z) {
        case 0: src = W0; dst = O0; break;
        case 1: src = W1; dst = O1; break;
        case 2: src = W2; dst = O2; break;
        default: src = W3; dst = O3; break;
    }
    __shared__ f16 t[64][68];
    const int e0 = blockIdx.y * 64, f0 = blockIdx.x * 64;
    const int tid = threadIdx.x;
    const int tf = (tid & 15) * 4;
    const int te = tid >> 4;
#pragma unroll
    for (int p = 0; p < 4; ++p) {
        const int e = te + p * 16;
        const float4 v = *reinterpret_cast<const float4*>(
            &src[(size_t)(e0 + e) * 2048 + f0 + tf]);
        t[tf + 0][e] = (f16)v.x; t[tf + 1][e] = (f16)v.y;
        t[tf + 2][e] = (f16)v.z; t[tf + 3][e] = (f16)v.w;
    }
    __syncthreads();
#pragma unroll
    for (int p = 0; p < 4; ++p) {
        const int f = (tid >> 4) + p * 16;
        const int e = (tid & 15) * 4;
        const f16x4 v = *reinterpret_cast<const f16x4*>(&t[f][e]);
        *reinterpret_cast<f16x4*>(&dst[(size_t)(f0 + f) * 2048 + e0 + e]) = v;
    }
}

__global__ __launch_bounds__(256) void softmax_rows_f16(
    const float* __restrict__ S, f16* __restrict__ A)
{
    const float* row = S + (size_t)blockIdx.x * 2048;
    f16* arow = A + (size_t)blockIdx.x * 2048;
    const int tid = threadIdx.x;

    float4 v0 = reinterpret_cast<const float4*>(row)[tid];
    float4 v1 = reinterpret_cast<const float4*>(row)[tid + 256];

    float m = fmaxf(fmaxf(fmaxf(v0.x, v0.y), fmaxf(v0.z, v0.w)),
                    fmaxf(fmaxf(v1.x, v1.y), fmaxf(v1.z, v1.w)));
#pragma unroll
    for (int off = 32; off > 0; off >>= 1) m = fmaxf(m, __shfl_xor(m, off));

    __shared__ float red[8];
    if ((tid & 63) == 0) red[tid >> 6] = m;
    __syncthreads();
    m = fmaxf(fmaxf(red[0], red[1]), fmaxf(red[2], red[3]));

    v0.x = __expf(v0.x - m); v0.y = __expf(v0.y - m);
    v0.z = __expf(v0.z - m); v0.w = __expf(v0.w - m);
    v1.x = __expf(v1.x - m); v1.y = __expf(v1.y - m);
    v1.z = __expf(v1.z - m); v1.w = __expf(v1.w - m);

    float s = v0.x + v0.y + v0.z + v0.w + v1.x + v1.y + v1.z + v1.w;
#pragma unroll
    for (int off = 32; off > 0; off >>= 1) s += __shfl_xor(s, off);
    if ((tid & 63) == 0) red[4 + (tid >> 6)] = s;
    __syncthreads();
    s = red[4] + red[5] + red[6] + red[7];

    const float inv = 1.0f / s;
    f16x4 a0 = {(f16)(v0.x * inv), (f16)(v0.y * inv), (f16)(v0.z * inv), (f16)(v0.w * inv)};
    f16x4 a1 = {(f16)(v1.x * inv), (f16)(v1.y * inv), (f16)(v1.z * inv), (f16)(v1.w * inv)};
    reinterpret_cast<f16x4*>(arow)[tid]       = a0;
    reinterpret_cast<f16x4*>(arow)[tid + 256] = a1;
}

// ---------------------------------------------------------------------------
extern "C" void kernel_launch(void* const* d_in, const int* in_sizes, int n_in,
                              void* d_out, int out_size, void* d_ws, size_t ws_size,
                              hipStream_t stream)
{
    const float* x  = (const float*)d_in[0];  // [2,2048,2048] == [4096,2048]
    const float* Wq = (const float*)d_in[1];
    const float* Wk = (const float*)d_in[2];
    const float* Wv = (const float*)d_in[3];
    const float* Wo = (const float*)d_in[4];
    float* out = (float*)d_out;               // [4096,2048] fp32

    // ws: xc | WqT WkT WvT WoT | QT | KT | V | S(fp32).  A=QT, AO=KT reuse.
    f16* ws16 = (f16*)d_ws;
    const size_t MATE = (size_t)BS * E;       // 8,388,608
    const size_t WMAT = (size_t)E * E;        // 4,194,304
    f16* xc  = ws16;
    f16* WqT = xc  + MATE;
    f16* WkT = WqT + WMAT;
    f16* WvT = WkT + WMAT;
    f16* WoT = WvT + WMAT;
    f16* QT  = WoT + WMAT;                    // [2][2048 f][2048 s]
    f16* KT  = QT  + MATE;
    f16* V   = KT  + MATE;                    // [4096 s][2048 f]
    float* S = (float*)(V + MATE);            // [2][2048 e][2048 f]
    f16* A   = QT;                            // reuse
    f16* AO  = KT;                            // reuse

    const dim3 blk(256);
    const long long BMATL = (long long)E * E;

    // 0) converters
    hipLaunchKernelGGL(conv_x_f16, dim3(2048), blk, 0, stream, x, xc, (int)(MATE / 4));
    hipLaunchKernelGGL(conv_wT, dim3(32, 32, 4), blk, 0, stream,
                       Wq, Wk, Wv, Wo, WqT, WkT, WvT, WoT);

    const dim3 gBig(E / BN, BS / BM, 1);      // 16 x 32
    const dim3 gSq (E / BN, E  / BM, BATCH);  // 16 x 16 x 2

    // 1) merged QKV: z=0 QT, z=1 KT (transposed epi), z=2 V (row-major)
    hipLaunchKernelGGL(qkv_f16, dim3(E / BN, BS / BM, 3), blk, 0, stream,
                       xc, WqT, WkT, WvT, QT, KT, V);

    // 2) S_b[e,f] = (1/8) * sum_s QT_b[e,s] KT_b[f,s]  -> fp32
    hipLaunchKernelGGL((gemm_f16<0, float>), gSq, blk, 0, stream,
                       QT, KT, S, SEQ, E, E, E, BMATL, BMATL, BMATL, 0.125f);

    // 3) softmax rows -> fp16 A
    hipLaunchKernelGGL(softmax_rows_f16, dim3(BATCH * E), blk, 0, stream, S, A);

    // 4) AO_b[s,e] = sum_f V_b[s,f] A_b[e,f]  -> fp16
    hipLaunchKernelGGL((gemm_f16<0, f16>), gSq, blk, 0, stream,
                       V, A, AO, E, E, E, E, BMATL, BMATL, BMATL, 1.0f);

    // 5) out = AO @ Wo  (B = WoT, k-contiguous) -> fp32
    hipLaunchKernelGGL((gemm_f16<0, float>), gBig, blk, 0, stream,
                       AO, WoT, out, E, E, E, E, 0LL, 0LL, 0LL, 1.0f);
}